// Round 1
// baseline (256.930 us; speedup 1.0000x reference)
//
#include <hip/hip_runtime.h>
#include <cstdint>
#include <cstddef>

// Problem constants (match reference)
#define NNODES 100000
#define FEATD  256
#define HIDD   256
#define NBATCH 512
#define FAN1   10          // hop-1 fanout (layer_infos[1])
#define FAN2   25          // hop-2 fanout (layer_infos[0])
#define NS1    (NBATCH*FAN1)   // 5120
#define MTOT   (NBATCH+NS1)    // 5632

// ---------------- kernel 1: s1 = adj[batch][:, :10] ----------------
__global__ void k_s1(const int* __restrict__ adj, const int* __restrict__ batch,
                     int* __restrict__ s1) {
    int i = blockIdx.x * 256 + threadIdx.x;
    if (i >= NS1) return;
    int b = i / FAN1;
    int j = i - b * FAN1;
    s1[i] = adj[(size_t)batch[b] * FAN2 + j];
}

// ---------------- kernel 2: neighbor means ----------------
// wave w < NS1          : h1nm[w] = mean_{k<25} features[adj[s1[w],k]]
// wave w in [NS1, MTOT) : h0nm[w-NS1] = mean_{j<10} features[s1[(w-NS1)*10+j]]
// One wave per output row: lane l holds floats [4l,4l+4) -> one dwordx4/lane
// covers the full 1KB row per load instruction (fully coalesced).
__global__ __launch_bounds__(256) void k_nmean(
    const float* __restrict__ feat, const int* __restrict__ adj,
    const int* __restrict__ s1, float* __restrict__ h1nm,
    float* __restrict__ h0nm) {
    int w    = blockIdx.x * 4 + (threadIdx.x >> 6);
    int lane = threadIdx.x & 63;
    float4 acc = make_float4(0.f, 0.f, 0.f, 0.f);
    if (w < NS1) {
        const int node = s1[w];
        const int* arow = adj + (size_t)node * FAN2;
        #pragma unroll
        for (int k = 0; k < FAN2; ++k) {
            int nb = arow[k];   // wave-uniform -> scalarized
            float4 v = *reinterpret_cast<const float4*>(
                feat + (size_t)nb * FEATD + lane * 4);
            acc.x += v.x; acc.y += v.y; acc.z += v.z; acc.w += v.w;
        }
        const float s = 1.0f / (float)FAN2;
        acc.x *= s; acc.y *= s; acc.z *= s; acc.w *= s;
        *reinterpret_cast<float4*>(h1nm + (size_t)w * FEATD + lane * 4) = acc;
    } else {
        int b = w - NS1;
        const int* srow = s1 + b * FAN1;
        #pragma unroll
        for (int j = 0; j < FAN1; ++j) {
            int nb = srow[j];
            float4 v = *reinterpret_cast<const float4*>(
                feat + (size_t)nb * FEATD + lane * 4);
            acc.x += v.x; acc.y += v.y; acc.z += v.z; acc.w += v.w;
        }
        const float s = 1.0f / (float)FAN1;
        acc.x *= s; acc.y *= s; acc.z *= s; acc.w *= s;
        *reinterpret_cast<float4*>(h0nm + (size_t)b * FEATD + lane * 4) = acc;
    }
}

// ---------------- kernel 3: layer-0 fused GEMM + relu ----------------
// Rows 0..511   : self = features[batch[r]],      neigh = h0nm[r]      -> H0
// Rows 512..5631: self = features[s1[r-512]],     neigh = h1nm[r-512]  -> H1
// out[r][n] = relu( sum_k self[r][k]*Ws[k][n] + neigh[r][k]*Wn[k][n] )
// Tile: 16 rows x 128 cols per block (grid 704 = 352 row-tiles x 2 col-halves).
// A tile (16 x 512 fp32 = 32KB LDS) staged once; W streamed from L1/L2.
__global__ __launch_bounds__(256) void k_layer0(
    const float* __restrict__ feat, const int* __restrict__ batch,
    const int* __restrict__ s1, const float* __restrict__ h0nm,
    const float* __restrict__ h1nm, const float* __restrict__ Ws,
    const float* __restrict__ Wn, float* __restrict__ H0,
    float* __restrict__ H1) {
    __shared__ float At[16][512];
    const int t  = threadIdx.x;
    const int rt = blockIdx.x >> 1;
    const int cb = (blockIdx.x & 1) * 128;
    const int rowBase = rt * 16;

    // Stage A: 16 rows x [self(256) | neigh(256)] = 2048 float4, 8/thread.
    #pragma unroll
    for (int i = 0; i < 8; ++i) {
        int flat = t + i * 256;      // float4 slot index
        int r    = flat >> 7;        // 128 float4 per row
        int c4   = flat & 127;
        int R    = rowBase + r;
        float4 v;
        if (c4 < 64) {
            int node = (R < NBATCH) ? batch[R] : s1[R - NBATCH];
            v = *reinterpret_cast<const float4*>(
                feat + (size_t)node * FEATD + c4 * 4);
        } else {
            const float* src = (R < NBATCH)
                ? (h0nm + (size_t)R * HIDD + (c4 - 64) * 4)
                : (h1nm + (size_t)(R - NBATCH) * HIDD + (c4 - 64) * 4);
            v = *reinterpret_cast<const float4*>(src);
        }
        *reinterpret_cast<float4*>(&At[r][c4 * 4]) = v;
    }
    __syncthreads();

    const int tcl = (t & 31) * 4;      // local col (0..124)
    const int tr  = (t >> 5) * 2;      // 2 rows per thread
    float4 acc0 = make_float4(0.f, 0.f, 0.f, 0.f);
    float4 acc1 = make_float4(0.f, 0.f, 0.f, 0.f);

    const float* Wh[2] = {Ws, Wn};
    #pragma unroll
    for (int half = 0; half < 2; ++half) {
        const float* W  = Wh[half] + cb + tcl;
        const int    ko = half * 256;
        for (int k4 = 0; k4 < 64; ++k4) {
            int k = k4 * 4;
            float4 a0 = *reinterpret_cast<const float4*>(&At[tr][ko + k]);
            float4 a1 = *reinterpret_cast<const float4*>(&At[tr + 1][ko + k]);
            const float* a0p = &a0.x;
            const float* a1p = &a1.x;
            #pragma unroll
            for (int kk = 0; kk < 4; ++kk) {
                float4 w = *reinterpret_cast<const float4*>(
                    W + (size_t)(k + kk) * HIDD);
                float av0 = a0p[kk], av1 = a1p[kk];
                acc0.x += av0 * w.x; acc0.y += av0 * w.y;
                acc0.z += av0 * w.z; acc0.w += av0 * w.w;
                acc1.x += av1 * w.x; acc1.y += av1 * w.y;
                acc1.z += av1 * w.z; acc1.w += av1 * w.w;
            }
        }
    }
    // relu
    acc0.x = fmaxf(acc0.x, 0.f); acc0.y = fmaxf(acc0.y, 0.f);
    acc0.z = fmaxf(acc0.z, 0.f); acc0.w = fmaxf(acc0.w, 0.f);
    acc1.x = fmaxf(acc1.x, 0.f); acc1.y = fmaxf(acc1.y, 0.f);
    acc1.z = fmaxf(acc1.z, 0.f); acc1.w = fmaxf(acc1.w, 0.f);

    const int col = cb + tcl;
    int R0 = rowBase + tr;
    int R1 = R0 + 1;
    float* d0 = (R0 < NBATCH) ? (H0 + (size_t)R0 * HIDD + col)
                              : (H1 + (size_t)(R0 - NBATCH) * HIDD + col);
    float* d1 = (R1 < NBATCH) ? (H0 + (size_t)R1 * HIDD + col)
                              : (H1 + (size_t)(R1 - NBATCH) * HIDD + col);
    *reinterpret_cast<float4*>(d0) = acc0;
    *reinterpret_cast<float4*>(d1) = acc1;
}

// ---------------- kernel 4: layer-1 GEMM + H1 mean + L2 norm ----------------
// A row b = [ H0[b] (256) | mean_{j<10} H1[b*10+j] (256) ], out = A @ [Ws1;Wn1]
// then row-wise L2 normalization. 8 rows x 256 cols per block; each wave owns
// 2 full rows so the norm is a wave-local shuffle reduction.
__global__ __launch_bounds__(256) void k_layer1(
    const float* __restrict__ H0, const float* __restrict__ H1,
    const float* __restrict__ Ws, const float* __restrict__ Wn,
    float* __restrict__ out) {
    __shared__ float At[8][512];
    const int t  = threadIdx.x;
    const int rb = blockIdx.x * 8;

    // Stage H0 part: 512 float4, 2/thread
    #pragma unroll
    for (int i = 0; i < 2; ++i) {
        int flat = t + i * 256;
        int r    = flat >> 6;       // 64 float4 per row
        int c4   = flat & 63;
        float4 v = *reinterpret_cast<const float4*>(
            H0 + (size_t)(rb + r) * HIDD + c4 * 4);
        *reinterpret_cast<float4*>(&At[r][c4 * 4]) = v;
    }
    // Stage H1-mean part: 512 float4 positions, each sums 10 source rows
    #pragma unroll
    for (int i = 0; i < 2; ++i) {
        int flat = t + i * 256;
        int r    = flat >> 6;
        int c4   = flat & 63;
        const float* base = H1 + (size_t)(rb + r) * FAN1 * HIDD + c4 * 4;
        float4 acc = make_float4(0.f, 0.f, 0.f, 0.f);
        #pragma unroll
        for (int j = 0; j < FAN1; ++j) {
            float4 v = *reinterpret_cast<const float4*>(base + (size_t)j * HIDD);
            acc.x += v.x; acc.y += v.y; acc.z += v.z; acc.w += v.w;
        }
        const float s = 1.0f / (float)FAN1;
        acc.x *= s; acc.y *= s; acc.z *= s; acc.w *= s;
        *reinterpret_cast<float4*>(&At[r][256 + c4 * 4]) = acc;
    }
    __syncthreads();

    const int tc = (t & 63) * 4;    // col, wave covers all 256
    const int tr = (t >> 6) * 2;    // 2 rows per wave
    float4 acc0 = make_float4(0.f, 0.f, 0.f, 0.f);
    float4 acc1 = make_float4(0.f, 0.f, 0.f, 0.f);

    const float* Wh[2] = {Ws, Wn};
    #pragma unroll
    for (int half = 0; half < 2; ++half) {
        const float* W  = Wh[half] + tc;
        const int    ko = half * 256;
        for (int k4 = 0; k4 < 64; ++k4) {
            int k = k4 * 4;
            float4 a0 = *reinterpret_cast<const float4*>(&At[tr][ko + k]);
            float4 a1 = *reinterpret_cast<const float4*>(&At[tr + 1][ko + k]);
            const float* a0p = &a0.x;
            const float* a1p = &a1.x;
            #pragma unroll
            for (int kk = 0; kk < 4; ++kk) {
                float4 w = *reinterpret_cast<const float4*>(
                    W + (size_t)(k + kk) * HIDD);
                float av0 = a0p[kk], av1 = a1p[kk];
                acc0.x += av0 * w.x; acc0.y += av0 * w.y;
                acc0.z += av0 * w.z; acc0.w += av0 * w.w;
                acc1.x += av1 * w.x; acc1.y += av1 * w.y;
                acc1.z += av1 * w.z; acc1.w += av1 * w.w;
            }
        }
    }

    // Row L2 norms: wave-local butterfly reductions
    float p0 = acc0.x*acc0.x + acc0.y*acc0.y + acc0.z*acc0.z + acc0.w*acc0.w;
    float p1 = acc1.x*acc1.x + acc1.y*acc1.y + acc1.z*acc1.z + acc1.w*acc1.w;
    #pragma unroll
    for (int off = 32; off >= 1; off >>= 1) {
        p0 += __shfl_xor(p0, off);
        p1 += __shfl_xor(p1, off);
    }
    float n0 = fmaxf(sqrtf(p0), 1e-12f);
    float n1 = fmaxf(sqrtf(p1), 1e-12f);
    float inv0 = 1.0f / n0;
    float inv1 = 1.0f / n1;
    acc0.x *= inv0; acc0.y *= inv0; acc0.z *= inv0; acc0.w *= inv0;
    acc1.x *= inv1; acc1.y *= inv1; acc1.z *= inv1; acc1.w *= inv1;

    *reinterpret_cast<float4*>(out + (size_t)(rb + tr) * HIDD + tc)     = acc0;
    *reinterpret_cast<float4*>(out + (size_t)(rb + tr + 1) * HIDD + tc) = acc1;
}

extern "C" void kernel_launch(void* const* d_in, const int* in_sizes, int n_in,
                              void* d_out, int out_size, void* d_ws, size_t ws_size,
                              hipStream_t stream) {
    const float* feat  = (const float*)d_in[0];   // [100000,256]
    const int*   adj   = (const int*)d_in[1];     // [100000,25]
    const int*   batch = (const int*)d_in[2];     // [512]
    const float* Ws0   = (const float*)d_in[3];   // [256,256]
    const float* Wn0   = (const float*)d_in[4];
    const float* Ws1   = (const float*)d_in[5];
    const float* Wn1   = (const float*)d_in[6];
    float* out = (float*)d_out;                   // [512,256]

    // Workspace layout (bytes); total ~11.6 MB
    char* ws = (char*)d_ws;
    int*   s1   = (int*)(ws + 0);                      //  5120 * 4
    float* h0nm = (float*)(ws + 32768);                //  512*256*4 = 512KB
    float* h1nm = (float*)(ws + 32768 + 524288);       // 5120*256*4 = 5MB
    float* H0   = (float*)(ws + 32768 + 524288 + 5242880);
    float* H1   = (float*)(ws + 32768 + 524288 + 5242880 + 524288);

    k_s1<<<(NS1 + 255) / 256, 256, 0, stream>>>(adj, batch, s1);
    k_nmean<<<MTOT / 4, 256, 0, stream>>>(feat, adj, s1, h1nm, h0nm);
    k_layer0<<<(MTOT / 16) * 2, 256, 0, stream>>>(feat, batch, s1, h0nm, h1nm,
                                                  Ws0, Wn0, H0, H1);
    k_layer1<<<NBATCH / 8, 256, 0, stream>>>(H0, H1, Ws1, Wn1, out);
}

// Round 2
// 209.186 us; speedup vs baseline: 1.2282x; 1.2282x over previous
//
#include <hip/hip_runtime.h>
#include <cstdint>
#include <cstddef>

#define NNODES 100000
#define FEATD  256
#define HIDD   256
#define NBATCH 512
#define FAN1   10            // hop-1 fanout
#define FAN2   25            // hop-2 fanout
#define NS1    (NBATCH*FAN1) // 5120
#define MTOT   (NBATCH+NS1)  // 5632

typedef __attribute__((ext_vector_type(8))) short short8;
typedef __attribute__((ext_vector_type(4))) float f32x4;

__device__ __forceinline__ unsigned short f2bf(float f) {
    unsigned int u = __float_as_uint(f);
    unsigned int r = (u + 0x7fffu + ((u >> 16) & 1u)) >> 16;
    return (unsigned short)r;
}

// ---------------- kernel 1: W0 convert + transpose ----------------
// B0t[n][k] (256 x 512 bf16): k<256 from Ws0[k][n], k>=256 from Wn0[k-256][n].
__global__ __launch_bounds__(256) void k_wcvt(
    const float* __restrict__ Ws0, const float* __restrict__ Wn0,
    unsigned short* __restrict__ B0t) {
    int i4 = (blockIdx.x * 256 + threadIdx.x) * 4;   // flat over 2*65536
    const float* W = (i4 < 65536) ? Ws0 : Wn0;
    int base = i4 & 65535;
    int kl   = base >> 8;          // row within W
    int n    = base & 255;         // col base (mult of 4)
    int k    = (i4 < 65536) ? kl : (kl + 256);
    float4 v = *reinterpret_cast<const float4*>(W + base);
    B0t[(size_t)(n + 0) * 512 + k] = f2bf(v.x);
    B0t[(size_t)(n + 1) * 512 + k] = f2bf(v.y);
    B0t[(size_t)(n + 2) * 512 + k] = f2bf(v.z);
    B0t[(size_t)(n + 3) * 512 + k] = f2bf(v.w);
}

// ---------------- kernel 2: gather + neighbor-mean + bf16 pack ----------------
// One wave per A0 row. Row w<512: self=feat[batch[w]], neigh=mean_{j<10}
// feat[adj[batch[w]*25+j]]. Row w>=512 (i=w-512,b=i/10,j=i%10):
// node=adj[batch[b]*25+j]; self=feat[node], neigh=mean_{k<25} feat[adj[node*25+k]].
// A0[w] = [bf16(self)(256) | bf16(neigh)(256)].
__global__ __launch_bounds__(256) void k_nmean_pack(
    const float* __restrict__ feat, const int* __restrict__ adj,
    const int* __restrict__ batch, unsigned short* __restrict__ A0) {
    const int w    = blockIdx.x * 4 + (threadIdx.x >> 6);
    const int lane = threadIdx.x & 63;

    int node;
    if (w < NBATCH) {
        node = batch[w];
    } else {
        int i = w - NBATCH;
        int b = i / FAN1;
        int j = i - b * FAN1;
        node = adj[(size_t)batch[b] * FAN2 + j];
    }
    const float* selfp = feat + (size_t)node * FEATD + lane * 4;
    float4 selfv = *reinterpret_cast<const float4*>(selfp);

    const int* arow = adj + (size_t)node * FAN2;
    int myidx = (lane < FAN2) ? arow[lane] : 0;

    float4 acc = make_float4(0.f, 0.f, 0.f, 0.f);
    if (w < NBATCH) {
        #pragma unroll
        for (int k = 0; k < FAN1; ++k) {
            int nb = __shfl(myidx, k);
            float4 v = *reinterpret_cast<const float4*>(
                feat + (size_t)nb * FEATD + lane * 4);
            acc.x += v.x; acc.y += v.y; acc.z += v.z; acc.w += v.w;
        }
        const float s = 1.0f / (float)FAN1;
        acc.x *= s; acc.y *= s; acc.z *= s; acc.w *= s;
    } else {
        #pragma unroll
        for (int k = 0; k < FAN2; ++k) {
            int nb = __shfl(myidx, k);
            float4 v = *reinterpret_cast<const float4*>(
                feat + (size_t)nb * FEATD + lane * 4);
            acc.x += v.x; acc.y += v.y; acc.z += v.z; acc.w += v.w;
        }
        const float s = 1.0f / (float)FAN2;
        acc.x *= s; acc.y *= s; acc.z *= s; acc.w *= s;
    }

    ushort4 ps, pn;
    ps.x = f2bf(selfv.x); ps.y = f2bf(selfv.y);
    ps.z = f2bf(selfv.z); ps.w = f2bf(selfv.w);
    pn.x = f2bf(acc.x);   pn.y = f2bf(acc.y);
    pn.z = f2bf(acc.z);   pn.w = f2bf(acc.w);
    unsigned short* dst = A0 + (size_t)w * 512;
    *reinterpret_cast<ushort4*>(dst + lane * 4)       = ps;
    *reinterpret_cast<ushort4*>(dst + 256 + lane * 4) = pn;
}

// ---------------- kernel 3: layer-0 bf16 MFMA GEMM + relu ----------------
// C[5632][256] = relu(A0[5632][512] @ B0[512][256]); rows<512 -> H0, else H1.
// 64x64 tile/block, 4 waves (each 16 rows x 64 cols), BK=64, 16x16x32 mfma.
// LDS padded to 72 shorts/row: fragment reads are 2-way bank aliased (free).
__global__ __launch_bounds__(256) void k_gemm0(
    const unsigned short* __restrict__ A0, const unsigned short* __restrict__ B0t,
    float* __restrict__ H0, float* __restrict__ H1) {
    __shared__ __align__(16) unsigned short As[64][72];
    __shared__ __align__(16) unsigned short Bs[64][72];
    const int t   = threadIdx.x;
    const int wv  = t >> 6;
    const int l   = t & 63;
    const int q   = l >> 4;     // quad
    const int m15 = l & 15;
    const int rt  = blockIdx.x >> 2;       // 88 row tiles
    const int ct  = blockIdx.x & 3;        // 4 col tiles
    const int r0  = rt * 64, c0 = ct * 64;

    f32x4 acc[4];
    #pragma unroll
    for (int f = 0; f < 4; ++f) acc[f] = (f32x4)0.f;

    for (int kt = 0; kt < 8; ++kt) {
        const int k0 = kt * 64;
        // stage A tile: 512 x 16B slots, 2 per thread
        #pragma unroll
        for (int i = 0; i < 2; ++i) {
            int s = t + i * 256;
            int row = s >> 3, k8 = (s & 7) * 8;
            *reinterpret_cast<short8*>(&As[row][k8]) =
                *reinterpret_cast<const short8*>(
                    A0 + (size_t)(r0 + row) * 512 + k0 + k8);
        }
        // stage B tile from pre-transposed B0t: Bs[n][k]
        #pragma unroll
        for (int i = 0; i < 2; ++i) {
            int s = t + i * 256;
            int nl = s >> 3, k8 = (s & 7) * 8;
            *reinterpret_cast<short8*>(&Bs[nl][k8]) =
                *reinterpret_cast<const short8*>(
                    B0t + (size_t)(c0 + nl) * 512 + k0 + k8);
        }
        __syncthreads();
        #pragma unroll
        for (int s = 0; s < 2; ++s) {
            const int kk = q * 8 + s * 32;
            short8 a = *reinterpret_cast<const short8*>(&As[wv * 16 + m15][kk]);
            #pragma unroll
            for (int f = 0; f < 4; ++f) {
                short8 b = *reinterpret_cast<const short8*>(&Bs[f * 16 + m15][kk]);
                acc[f] = __builtin_amdgcn_mfma_f32_16x16x32_bf16(a, b, acc[f], 0, 0, 0);
            }
        }
        __syncthreads();
    }

    // epilogue: D row = q*4 + reg, col = m15 (per 16x16 C/D layout), + relu
    #pragma unroll
    for (int f = 0; f < 4; ++f) {
        const int n = c0 + f * 16 + m15;
        #pragma unroll
        for (int j = 0; j < 4; ++j) {
            int m = r0 + wv * 16 + q * 4 + j;
            float v = fmaxf(acc[f][j], 0.f);
            if (m < NBATCH)
                H0[(size_t)m * HIDD + n] = v;
            else
                H1[(size_t)(m - NBATCH) * HIDD + n] = v;
        }
    }
}

// ---------------- kernel 4: layer-1 GEMM + H1 mean + L2 norm (fp32) ----------------
// 4 rows/block (128 blocks); each wave owns one full 256-col row.
__global__ __launch_bounds__(256) void k_layer1(
    const float* __restrict__ H0, const float* __restrict__ H1,
    const float* __restrict__ Ws, const float* __restrict__ Wn,
    float* __restrict__ out) {
    __shared__ float At[4][512];
    const int t  = threadIdx.x;
    const int rb = blockIdx.x * 4;

    // Stage H0 part: 256 float4, 1/thread
    {
        int r = t >> 6, c4 = t & 63;
        *reinterpret_cast<float4*>(&At[r][c4 * 4]) =
            *reinterpret_cast<const float4*>(H0 + (size_t)(rb + r) * HIDD + c4 * 4);
    }
    // Stage H1-mean part: 256 slots, each averages 10 rows
    {
        int r = t >> 6, c4 = t & 63;
        const float* base = H1 + (size_t)(rb + r) * FAN1 * HIDD + c4 * 4;
        float4 acc = make_float4(0.f, 0.f, 0.f, 0.f);
        #pragma unroll
        for (int j = 0; j < FAN1; ++j) {
            float4 v = *reinterpret_cast<const float4*>(base + (size_t)j * HIDD);
            acc.x += v.x; acc.y += v.y; acc.z += v.z; acc.w += v.w;
        }
        const float s = 1.0f / (float)FAN1;
        acc.x *= s; acc.y *= s; acc.z *= s; acc.w *= s;
        *reinterpret_cast<float4*>(&At[r][256 + c4 * 4]) = acc;
    }
    __syncthreads();

    const int wv = t >> 6;        // row within block
    const int tc = (t & 63) * 4;  // col
    float4 acc = make_float4(0.f, 0.f, 0.f, 0.f);

    const float* Wh[2] = {Ws, Wn};
    #pragma unroll
    for (int half = 0; half < 2; ++half) {
        const float* W  = Wh[half] + tc;
        const int    ko = half * 256;
        for (int k4 = 0; k4 < 64; ++k4) {
            int k = k4 * 4;
            float4 a = *reinterpret_cast<const float4*>(&At[wv][ko + k]);
            const float* ap = &a.x;
            #pragma unroll
            for (int kk = 0; kk < 4; ++kk) {
                float4 w = *reinterpret_cast<const float4*>(W + (size_t)(k + kk) * HIDD);
                float av = ap[kk];
                acc.x += av * w.x; acc.y += av * w.y;
                acc.z += av * w.z; acc.w += av * w.w;
            }
        }
    }

    float p = acc.x*acc.x + acc.y*acc.y + acc.z*acc.z + acc.w*acc.w;
    #pragma unroll
    for (int off = 32; off >= 1; off >>= 1) p += __shfl_xor(p, off);
    float inv = 1.0f / fmaxf(sqrtf(p), 1e-12f);
    acc.x *= inv; acc.y *= inv; acc.z *= inv; acc.w *= inv;
    *reinterpret_cast<float4*>(out + (size_t)(rb + wv) * HIDD + tc) = acc;
}

extern "C" void kernel_launch(void* const* d_in, const int* in_sizes, int n_in,
                              void* d_out, int out_size, void* d_ws, size_t ws_size,
                              hipStream_t stream) {
    const float* feat  = (const float*)d_in[0];
    const int*   adj   = (const int*)d_in[1];
    const int*   batch = (const int*)d_in[2];
    const float* Ws0   = (const float*)d_in[3];
    const float* Wn0   = (const float*)d_in[4];
    const float* Ws1   = (const float*)d_in[5];
    const float* Wn1   = (const float*)d_in[6];
    float* out = (float*)d_out;

    // ws layout (bytes): A0 bf16 [5632][512] @0 (5,767,168); B0t bf16 [256][512]
    // @5,767,168 (262,144); H0 f32 [512][256] @6,029,312 (524,288);
    // H1 f32 [5120][256] @6,553,600 (5,242,880). Total ~11.8 MB.
    char* ws = (char*)d_ws;
    unsigned short* A0  = (unsigned short*)(ws + 0);
    unsigned short* B0t = (unsigned short*)(ws + 5767168);
    float*          H0  = (float*)(ws + 6029312);
    float*          H1  = (float*)(ws + 6553600);

    k_wcvt<<<128, 256, 0, stream>>>(Ws0, Wn0, B0t);
    k_nmean_pack<<<MTOT / 4, 256, 0, stream>>>(feat, adj, batch, A0);
    k_gemm0<<<(MTOT / 64) * 4, 256, 0, stream>>>(A0, B0t, H0, H1);
    k_layer1<<<NBATCH / 4, 256, 0, stream>>>(H0, H1, Ws1, Wn1, out);
}